// Round 6
// baseline (135.459 us; speedup 1.0000x reference)
//
#include <hip/hip_runtime.h>
#include <stdint.h>

#define HH   512
#define WWI  512
#define HWN  (HH*WWI)
#define KK   256
#define WSR  32
#define SSW  64
#define PDD  5
#define RPB  8                         // rows per k_front block
#define HALO 5
#define SROWS (RPB + 2*HALO)           // 18
#define NBLK (HH / RPB)                // 64
#define CPB  64                        // candidate slots per block
#define CAND_CAP (NBLK * CPB)          // 4096

// workspace byte offsets
#define OFF_MAXP   0u
#define OFF_LAB    1048576u
#define OFF_BITS   2097152u            // 256*64*8 = 131072
#define OFF_AREA   2228224u
#define OFF_MSUM   2229248u
#define OFF_WY0    2230272u
#define OFF_WX0    2231296u
#define OFF_FINAL  2232320u
#define OFF_CNT    2233344u
#define OFF_ADJ    2233352u            // 8-aligned; 256*4*8 = 8192
#define OFF_CAND   2241544u            // 8-aligned; 4096*8 = 32768
#define OFF_RANK   2274312u            // 4096*4 = 16384

__device__ __forceinline__ float sigm(float v) {
    return 1.0f / (1.0f + expf(-v));
}

// Fused front end: sigmoid + separable 11x11 window max + peak emit into
// per-block private candidate regions + all zero-fills.
// Vertical max is register-only (rows in regs, constant indices); only the
// horizontal pass goes through LDS.
__global__ __launch_bounds__(256) void k_front(const float* __restrict__ x4,
        unsigned long long* __restrict__ cand,
        unsigned int* __restrict__ maxp, int* __restrict__ lab,
        unsigned long long* __restrict__ bits,
        float* __restrict__ areas, float* __restrict__ msum,
        int* __restrict__ iy0, int* __restrict__ ix0,
        int* __restrict__ rankbuf, int* __restrict__ cnt) {
    __shared__ float vm[RPB][WWI];     // vertical 11-max, 16 KB
    __shared__ int lcnt;
    int t = threadIdx.x, bid = blockIdx.x;
    int r0 = bid * RPB;
    if (t == 0) lcnt = 0;
    if (t < CPB) cand[bid * CPB + t] = 0ull;   // zero own candidate region

    float s0[SROWS], s1[SROWS];        // sigmoid rows for cols t and t+256
    #pragma unroll
    for (int hr = 0; hr < SROWS; ++hr) {
        int gr = r0 - HALO + hr; gr = gr < 0 ? 0 : (gr > HH-1 ? HH-1 : gr);
        const float* row = x4 + gr * WWI;
        s0[hr] = sigm(row[t]);
        s1[hr] = sigm(row[t + 256]);
    }
    #pragma unroll
    for (int rr = 0; rr < RPB; ++rr) {
        float a = s0[rr], b = s1[rr];
        #pragma unroll
        for (int d = 1; d < 11; ++d) { a = fmaxf(a, s0[rr+d]); b = fmaxf(b, s1[rr+d]); }
        vm[rr][t] = a; vm[rr][t+256] = b;
    }
    __syncthreads();
    // horizontal 11-max of vm + peak test for own 8 rows
    #pragma unroll
    for (int rr = 0; rr < RPB; ++rr) {
        int gy = r0 + rr;
        {
            int c = t;
            float m = s0[rr + HALO];
            if (m > 0.7f) {
                int c0 = c-5 < 0 ? 0 : c-5, c1 = c+5 > 511 ? 511 : c+5;
                float v = -1.0f;
                for (int cc = c0; cc <= c1; ++cc) v = fmaxf(v, vm[rr][cc]);
                if (m == v) {
                    int slot = atomicAdd(&lcnt, 1);
                    if (slot < CPB) {
                        unsigned p = (unsigned)(gy * WWI + c);
                        cand[bid * CPB + slot] =
                            ((unsigned long long)__float_as_uint(m) << 32) |
                            (unsigned long long)(0xFFFFFFFFu - p);
                    }
                }
            }
        }
        {
            int c = t + 256;
            float m = s1[rr + HALO];
            if (m > 0.7f) {
                int c0 = c-5, c1 = c+5 > 511 ? 511 : c+5;
                float v = -1.0f;
                for (int cc = c0; cc <= c1; ++cc) v = fmaxf(v, vm[rr][cc]);
                if (m == v) {
                    int slot = atomicAdd(&lcnt, 1);
                    if (slot < CPB) {
                        unsigned p = (unsigned)(gy * WWI + c);
                        cand[bid * CPB + slot] =
                            ((unsigned long long)__float_as_uint(m) << 32) |
                            (unsigned long long)(0xFFFFFFFFu - p);
                    }
                }
            }
        }
    }
    // fused zero fills (grid: 64*256 = 16384 threads)
    int g = bid * 256 + t;
    #pragma unroll
    for (int rep = 0; rep < 16; ++rep) {
        int idx = g + rep * 16384;
        maxp[idx] = 0u;
        lab[idx] = 0;
    }
    if (g < KK * 64) bits[g] = 0ull;
    if (g < CAND_CAP) rankbuf[g] = 0;
    if (g < KK) { areas[g] = 0.0f; msum[g] = 0.0f; iy0[g] = 0; ix0[g] = 0; }
    if (g == 0) *cnt = 0;
}

// Partial descending-sort ranks: block (bx,by) ranks chunk bx against key
// chunk by (LDS-staged). Zero keys are padding (< every real key).
// by==0 row also accumulates the valid-candidate count.
__global__ __launch_bounds__(256) void k_rank1(const unsigned long long* __restrict__ cand,
                                               int* __restrict__ rankbuf,
                                               int* __restrict__ cnt) {
    __shared__ unsigned long long kl[256];
    int tid = threadIdx.x;
    int ibase = blockIdx.x * 256, jbase = blockIdx.y * 256;
    kl[tid] = cand[jbase + tid];
    unsigned long long my = cand[ibase + tid];
    if (blockIdx.y == 0) {
        unsigned long long bal = __ballot(my != 0ull);
        if ((tid & 63) == 0) atomicAdd(cnt, (int)__popcll(bal));
    }
    __syncthreads();
    if (my == 0ull) return;
    int r0 = 0, r1 = 0, r2 = 0, r3 = 0, r4 = 0, r5 = 0, r6 = 0, r7 = 0;
    #pragma unroll 4
    for (int j = 0; j < 256; j += 8) {
        unsigned long long a0 = kl[j+0], a1 = kl[j+1], a2 = kl[j+2], a3 = kl[j+3];
        unsigned long long a4 = kl[j+4], a5 = kl[j+5], a6 = kl[j+6], a7 = kl[j+7];
        r0 += (a0 > my); r1 += (a1 > my); r2 += (a2 > my); r3 += (a3 > my);
        r4 += (a4 > my); r5 += (a5 > my); r6 += (a6 > my); r7 += (a7 > my);
    }
    int r = (r0 + r1) + (r2 + r3) + ((r4 + r5) + (r6 + r7));
    if (r) atomicAdd(&rankbuf[ibase + tid], r);
}

// Windowed classifier, launched by CANDIDATE index (self-places by rank).
// Tail blocks (bid >= CAND_CAP) zero probs for unfilled rank slots.
__global__ __launch_bounds__(256) void k_win2(const float* __restrict__ x,
        const float* __restrict__ wc, const float* __restrict__ bc,
        const unsigned long long* __restrict__ cand,
        const int* __restrict__ rankbuf, const int* __restrict__ cnt,
        float* __restrict__ probs, unsigned int* __restrict__ maxp,
        unsigned long long* __restrict__ bits,
        float* __restrict__ areas, float* __restrict__ msum,
        int* __restrict__ iy0, int* __restrict__ ix0) {
    int bid = blockIdx.x, tid = threadIdx.x;
    if (bid >= CAND_CAP) {
        int j = bid - CAND_CAP;
        int c = *cnt; if (c > KK) c = KK;
        if (j >= c) for (int i = tid; i < SSW * SSW; i += 256) probs[j * 4096 + i] = 0.0f;
        return;
    }
    unsigned long long my = cand[bid];
    if (my == 0ull) return;
    int k = rankbuf[bid];
    if (k >= KK) return;
    unsigned pp = 0xFFFFFFFFu - (unsigned)(my & 0xFFFFFFFFull);
    int cy = (int)(pp >> 9), cx = (int)(pp & 511);
    int wy = cy < WSR ? WSR : (cy > HH - WSR ? HH - WSR : cy);
    int wx = cx < WSR ? WSR : (cx > WWI - WSR ? WWI - WSR : cx);
    int gy0 = wy - WSR, gx0 = wx - WSR;
    if (tid == 0) { iy0[k] = gy0; ix0[k] = gx0; }

    __shared__ unsigned long long rb[64];
    __shared__ float sA, sM;
    if (tid < 64) rb[tid] = 0ull;
    if (tid == 0) { sA = 0.0f; sM = 0.0f; }
    __syncthreads();
    float w0 = wc[0], w1 = wc[1], w2 = wc[2], w3 = wc[3], b = bc[0];
    float cyf = (float)cy, cxf = (float)cx;
    int r = tid >> 2, cb = (tid & 3) << 4;
    int gy = gy0 + r;
    float gyf = (float)gy;
    const float* x0 = x;
    const float* x1 = x + HWN;
    const float* x2 = x + 2 * HWN;
    const float* x3 = x + 3 * HWN;
    const float* x4p = x + 4 * HWN;
    unsigned int bloc = 0;
    float aA = 0.0f, aM = 0.0f;
    int rowbase = gy * WWI;
    for (int q = 0; q < 16; ++q) {
        int col = cb + q;
        int gx = gx0 + col;
        int g = rowbase + gx;
        float d0 = __fsub_rn(__fadd_rn(x0[g], gyf), cyf);
        float d1 = __fsub_rn(__fadd_rn(x1[g], (float)gx), cxf);
        float s0 = x2[g], s1 = x3[g];
        float t = __fadd_rn(
                    __fadd_rn(
                      __fadd_rn(
                        __fadd_rn(__fmul_rn(w0, d0), __fmul_rn(w1, d1)),
                        __fmul_rn(w2, s0)),
                      __fmul_rn(w3, s1)),
                    b);
        float pr = sigm(t);
        probs[k * 4096 + r * 64 + col] = pr;
        if (pr > 0.53f) {
            bloc |= (1u << q);
            aA += 1.0f;
            aM += sigm(x4p[g]);
            atomicMax(&maxp[g], __float_as_uint(pr));
        }
    }
    if (bloc) atomicOr(&rb[r], (unsigned long long)bloc << cb);
    atomicAdd(&sA, aA);
    atomicAdd(&sM, aM);
    __syncthreads();
    if (tid < 64) bits[k * 64 + tid] = rb[tid];
    if (tid == 0) { areas[k] = sA; msum[k] = sM; }
}

// Fused: blocks [0,256) = winner labeling; blocks [256,512) = pairwise IoU.
__global__ __launch_bounds__(256) void k_labpairs(const int* __restrict__ cnt,
        const int* __restrict__ iy0, const int* __restrict__ ix0,
        const float* __restrict__ probs, const unsigned int* __restrict__ maxp,
        int* __restrict__ lab,
        const unsigned long long* __restrict__ bits,
        const float* __restrict__ areas,
        unsigned long long* __restrict__ adj) {
    int bid = blockIdx.x, tid = threadIdx.x;
    if (bid < KK) {
        int k = bid;
        int c = *cnt; if (c > KK) c = KK;
        if (k >= c) return;
        int gy0 = iy0[k], gx0 = ix0[k];
        for (int q = 0; q < 16; ++q) {
            int p = tid + (q << 8);
            float pr = probs[k * 4096 + p];
            if (pr > 0.53f) {
                int r = p >> 6, cc = p & 63;
                int g = (gy0 + r) * WWI + gx0 + cc;
                if (pr >= __uint_as_float(maxp[g])) atomicMax(&lab[g], k + 1);
            }
        }
    } else {
        int a = bid - KK, b = tid;
        __shared__ unsigned long long rowA[64];
        __shared__ int say0, sax0;
        if (tid < 64) rowA[tid] = bits[a * 64 + tid];
        if (tid == 0) { say0 = iy0[a]; sax0 = ix0[a]; }
        __syncthreads();
        int ay0 = say0, ax0 = sax0;
        int by0 = iy0[b], bx0 = ix0[b];
        int yl = max(ay0, by0), yh = min(ay0 + SSW, by0 + SSW);
        int xl = max(ax0, bx0), xh = min(ax0 + SSW, bx0 + SSW);
        int inter = 0;
        if (yl < yh && xl < xh) {
            int wdt = xh - xl;
            unsigned long long cmask = (wdt >= 64) ? ~0ull : ((1ull << wdt) - 1ull);
            int sa = xl - ax0, sb = xl - bx0;
            for (int y = yl; y < yh; ++y) {
                unsigned long long wa = rowA[y - ay0] >> sa;
                unsigned long long wb = bits[b * 64 + (y - by0)] >> sb;
                inter += __popcll(wa & wb & cmask);
            }
        }
        float fi = (float)inter;
        float uni = __fsub_rn(__fadd_rn(areas[a], areas[b]), fi);
        bool adjb = (fi / fmaxf(uni, 1.0f)) > 0.3f;
        unsigned long long bal = __ballot(adjb);
        if ((tid & 63) == 0) adj[a * 4 + (tid >> 6)] = bal;
    }
}

__global__ __launch_bounds__(256) void k_cc(const unsigned long long* __restrict__ adj,
        const float* __restrict__ areas, const float* __restrict__ msum,
        const int* __restrict__ cnt, int* __restrict__ finalmap) {
    __shared__ unsigned long long adjS[KK][4];
    __shared__ int lbl[KK];
    __shared__ unsigned char rem[KK];
    __shared__ int changed;
    int i = threadIdx.x;
    for (int w = 0; w < 4; ++w) adjS[i][w] = adj[i * 4 + w];
    lbl[i] = i;
    __syncthreads();
    for (int it = 0; it < 32; ++it) {
        int m = KK;
        for (int w = 0; w < 4; ++w) {
            unsigned long long bb = adjS[i][w];
            while (bb) {
                int j = __ffsll((unsigned long long)bb) - 1;
                int v = lbl[(w << 6) | j];
                m = v < m ? v : m;
                bb &= bb - 1;
            }
        }
        if (i == 0) changed = 0;
        __syncthreads();
        if (m != lbl[i]) { lbl[i] = m; atomicOr(&changed, 1); }
        __syncthreads();
        if (!changed) break;   // converged: further iterations are identity
    }
    float area = areas[i];
    bool validf = i < *cnt;
    float mean = msum[i] / fmaxf(area, 1.0f);
    rem[i] = (unsigned char)(!((mean > 0.0f) && (area > 10.0f) && validf));
    __syncthreads();
    int root = lbl[i];
    int rc = root < 255 ? root : 255;
    finalmap[i] = rem[rc] ? 0 : (root + 1);
}

__global__ void k_final(const int* __restrict__ lab, const int* __restrict__ finalmap,
                        float* __restrict__ labels) {
    int p = blockIdx.x * blockDim.x + threadIdx.x;
    if (p < HWN) {
        int l = lab[p];
        labels[p] = l > 0 ? (float)finalmap[l - 1] : 0.0f;
    }
}

extern "C" void kernel_launch(void* const* d_in, const int* in_sizes, int n_in,
                              void* d_out, int out_size, void* d_ws, size_t ws_size,
                              hipStream_t stream) {
    const float* x  = (const float*)d_in[0];
    const float* wc = (const float*)d_in[1];
    const float* bc = (const float*)d_in[2];
    float* labels = (float*)d_out;
    float* probs  = (float*)d_out + HWN;

    char* ws = (char*)d_ws;
    unsigned int*       maxp    = (unsigned int*)(ws + OFF_MAXP);
    int*                lab     = (int*)(ws + OFF_LAB);
    unsigned long long* bits    = (unsigned long long*)(ws + OFF_BITS);
    float*              areas   = (float*)(ws + OFF_AREA);
    float*              msum    = (float*)(ws + OFF_MSUM);
    int*                iy0     = (int*)(ws + OFF_WY0);
    int*                ix0     = (int*)(ws + OFF_WX0);
    int*                fmap    = (int*)(ws + OFF_FINAL);
    int*                cnt     = (int*)(ws + OFF_CNT);
    unsigned long long* adj     = (unsigned long long*)(ws + OFF_ADJ);
    unsigned long long* cand    = (unsigned long long*)(ws + OFF_CAND);
    int*                rankbuf = (int*)(ws + OFF_RANK);

    k_front   <<<NBLK, 256, 0, stream>>>(x + 4 * HWN, cand, maxp, lab, bits,
                                         areas, msum, iy0, ix0, rankbuf, cnt);
    k_rank1   <<<dim3(CAND_CAP / 256, CAND_CAP / 256), 256, 0, stream>>>(cand, rankbuf, cnt);
    k_win2    <<<CAND_CAP + KK, 256, 0, stream>>>(x, wc, bc, cand, rankbuf, cnt,
                                                  probs, maxp, bits, areas, msum, iy0, ix0);
    k_labpairs<<<2 * KK, 256, 0, stream>>>(cnt, iy0, ix0, probs, maxp, lab,
                                           bits, areas, adj);
    k_cc      <<<1, 256, 0, stream>>>(adj, areas, msum, cnt, fmap);
    k_final   <<<HWN / 256, 256, 0, stream>>>(lab, fmap, labels);
}

// Round 7
// 69.444 us; speedup vs baseline: 1.9506x; 1.9506x over previous
//
#include <hip/hip_runtime.h>
#include <stdint.h>

#define HH   512
#define WWI  512
#define HWN  (HH*WWI)
#define KK   256
#define WSR  32
#define SSW  64
#define PDD  5
#define RPB  8                         // rows per k_front block
#define HALO 5
#define SROWS (RPB + 2*HALO)           // 18
#define NBLK (HH / RPB)                // 64
#define CPB  64                        // candidate slots per block
#define CAND_CAP (NBLK * CPB)          // 4096

// workspace byte offsets
#define OFF_MAXP   0u
#define OFF_LAB    1048576u
#define OFF_BITS   2097152u            // 256*64*8 = 131072
#define OFF_AREA   2228224u
#define OFF_MSUM   2229248u
#define OFF_WY0    2230272u
#define OFF_WX0    2231296u
#define OFF_FINAL  2232320u
#define OFF_CNT    2233344u
#define OFF_ADJ    2233352u            // 8-aligned; 256*4*8 = 8192
#define OFF_CAND   2241544u            // 8-aligned; 4096*8 = 32768
#define OFF_RANK   2274312u            // 4096*4 = 16384

__device__ __forceinline__ float sigm(float v) {
    return 1.0f / (1.0f + expf(-v));
}

// Fused front end: sigmoid + separable 11x11 window max + peak emit into
// per-block private candidate regions + all zero-fills.
__global__ __launch_bounds__(256) void k_front(const float* __restrict__ x4,
        unsigned long long* __restrict__ cand,
        unsigned int* __restrict__ maxp, int* __restrict__ lab,
        unsigned long long* __restrict__ bits,
        float* __restrict__ areas, float* __restrict__ msum,
        int* __restrict__ iy0, int* __restrict__ ix0,
        int* __restrict__ rankbuf, int* __restrict__ cnt) {
    __shared__ float vm[RPB][WWI];     // vertical 11-max, 16 KB
    __shared__ int lcnt;
    int t = threadIdx.x, bid = blockIdx.x;
    int r0 = bid * RPB;
    if (t == 0) lcnt = 0;
    if (t < CPB) cand[bid * CPB + t] = 0ull;   // zero own candidate region

    float s0[SROWS], s1[SROWS];        // sigmoid rows for cols t and t+256
    #pragma unroll
    for (int hr = 0; hr < SROWS; ++hr) {
        int gr = r0 - HALO + hr; gr = gr < 0 ? 0 : (gr > HH-1 ? HH-1 : gr);
        const float* row = x4 + gr * WWI;
        s0[hr] = sigm(row[t]);
        s1[hr] = sigm(row[t + 256]);
    }
    #pragma unroll
    for (int rr = 0; rr < RPB; ++rr) {
        float a = s0[rr], b = s1[rr];
        #pragma unroll
        for (int d = 1; d < 11; ++d) { a = fmaxf(a, s0[rr+d]); b = fmaxf(b, s1[rr+d]); }
        vm[rr][t] = a; vm[rr][t+256] = b;
    }
    __syncthreads();
    // horizontal 11-max of vm + peak test for own 8 rows
    #pragma unroll
    for (int rr = 0; rr < RPB; ++rr) {
        int gy = r0 + rr;
        {
            int c = t;
            float m = s0[rr + HALO];
            if (m > 0.7f) {
                int c0 = c-5 < 0 ? 0 : c-5, c1 = c+5 > 511 ? 511 : c+5;
                float v = -1.0f;
                for (int cc = c0; cc <= c1; ++cc) v = fmaxf(v, vm[rr][cc]);
                if (m == v) {
                    int slot = atomicAdd(&lcnt, 1);
                    if (slot < CPB) {
                        unsigned p = (unsigned)(gy * WWI + c);
                        cand[bid * CPB + slot] =
                            ((unsigned long long)__float_as_uint(m) << 32) |
                            (unsigned long long)(0xFFFFFFFFu - p);
                    }
                }
            }
        }
        {
            int c = t + 256;
            float m = s1[rr + HALO];
            if (m > 0.7f) {
                int c0 = c-5, c1 = c+5 > 511 ? 511 : c+5;
                float v = -1.0f;
                for (int cc = c0; cc <= c1; ++cc) v = fmaxf(v, vm[rr][cc]);
                if (m == v) {
                    int slot = atomicAdd(&lcnt, 1);
                    if (slot < CPB) {
                        unsigned p = (unsigned)(gy * WWI + c);
                        cand[bid * CPB + slot] =
                            ((unsigned long long)__float_as_uint(m) << 32) |
                            (unsigned long long)(0xFFFFFFFFu - p);
                    }
                }
            }
        }
    }
    // fused zero fills (grid: 64*256 = 16384 threads)
    int g = bid * 256 + t;
    #pragma unroll
    for (int rep = 0; rep < 16; ++rep) {
        int idx = g + rep * 16384;
        maxp[idx] = 0u;
        lab[idx] = 0;
    }
    if (g < KK * 64) bits[g] = 0ull;
    if (g < CAND_CAP) rankbuf[g] = 0;
    if (g < KK) { areas[g] = 0.0f; msum[g] = 0.0f; iy0[g] = 0; ix0[g] = 0; }
    if (g == 0) *cnt = 0;
}

// Partial descending-sort ranks: block (bx,by) ranks chunk bx against key
// chunk by (LDS-staged). Zero keys are padding (< every real key).
__global__ __launch_bounds__(256) void k_rank1(const unsigned long long* __restrict__ cand,
                                               int* __restrict__ rankbuf,
                                               int* __restrict__ cnt) {
    __shared__ unsigned long long kl[256];
    int tid = threadIdx.x;
    int ibase = blockIdx.x * 256, jbase = blockIdx.y * 256;
    kl[tid] = cand[jbase + tid];
    unsigned long long my = cand[ibase + tid];
    if (blockIdx.y == 0) {
        unsigned long long bal = __ballot(my != 0ull);
        if ((tid & 63) == 0) atomicAdd(cnt, (int)__popcll(bal));
    }
    __syncthreads();
    if (my == 0ull) return;
    int r0 = 0, r1 = 0, r2 = 0, r3 = 0, r4 = 0, r5 = 0, r6 = 0, r7 = 0;
    #pragma unroll 4
    for (int j = 0; j < 256; j += 8) {
        unsigned long long a0 = kl[j+0], a1 = kl[j+1], a2 = kl[j+2], a3 = kl[j+3];
        unsigned long long a4 = kl[j+4], a5 = kl[j+5], a6 = kl[j+6], a7 = kl[j+7];
        r0 += (a0 > my); r1 += (a1 > my); r2 += (a2 > my); r3 += (a3 > my);
        r4 += (a4 > my); r5 += (a5 > my); r6 += (a6 > my); r7 += (a7 > my);
    }
    int r = (r0 + r1) + (r2 + r3) + ((r4 + r5) + (r6 + r7));
    if (r) atomicAdd(&rankbuf[ibase + tid], r);
}

// Windowed classifier, launched by CANDIDATE index (self-places by rank).
// Linear pixel mapping: p = q*256 + tid -> row uniform per wave, col = lane.
// All loads/stores coalesced; row bitmap via ballot (no LDS atomics).
__global__ __launch_bounds__(256) void k_win2(const float* __restrict__ x,
        const float* __restrict__ wc, const float* __restrict__ bc,
        const unsigned long long* __restrict__ cand,
        const int* __restrict__ rankbuf, const int* __restrict__ cnt,
        float* __restrict__ probs, unsigned int* __restrict__ maxp,
        unsigned long long* __restrict__ bits,
        float* __restrict__ areas, float* __restrict__ msum,
        int* __restrict__ iy0, int* __restrict__ ix0) {
    int bid = blockIdx.x, tid = threadIdx.x;
    if (bid >= CAND_CAP) {
        int j = bid - CAND_CAP;
        int c = *cnt; if (c > KK) c = KK;
        if (j >= c) for (int i = tid; i < SSW * SSW; i += 256) probs[j * 4096 + i] = 0.0f;
        return;
    }
    unsigned long long my = cand[bid];
    if (my == 0ull) return;
    int k = rankbuf[bid];
    if (k >= KK) return;
    unsigned pp = 0xFFFFFFFFu - (unsigned)(my & 0xFFFFFFFFull);
    int cy = (int)(pp >> 9), cx = (int)(pp & 511);
    int wy = cy < WSR ? WSR : (cy > HH - WSR ? HH - WSR : cy);
    int wx = cx < WSR ? WSR : (cx > WWI - WSR ? WWI - WSR : cx);
    int gy0 = wy - WSR, gx0 = wx - WSR;
    if (tid == 0) { iy0[k] = gy0; ix0[k] = gx0; }

    __shared__ float sA, sM;
    if (tid == 0) { sA = 0.0f; sM = 0.0f; }
    __syncthreads();
    float w0 = wc[0], w1 = wc[1], w2 = wc[2], w3 = wc[3], b = bc[0];
    float cyf = (float)cy, cxf = (float)cx;
    const float* x0 = x;
    const float* x1 = x + HWN;
    const float* x2 = x + 2 * HWN;
    const float* x3 = x + 3 * HWN;
    const float* x4p = x + 4 * HWN;
    int lane = tid & 63;
    float aA = 0.0f, aM = 0.0f;
    #pragma unroll 4
    for (int q = 0; q < 16; ++q) {
        int p = (q << 8) + tid;        // 0..4095
        int row = p >> 6;              // uniform per wave
        int col = p & 63;              // = lane
        int gy = gy0 + row, gx = gx0 + col;
        int g = gy * WWI + gx;
        float gyf = (float)gy;
        float d0 = __fsub_rn(__fadd_rn(x0[g], gyf), cyf);
        float d1 = __fsub_rn(__fadd_rn(x1[g], (float)gx), cxf);
        float s0 = x2[g], s1 = x3[g];
        float t = __fadd_rn(
                    __fadd_rn(
                      __fadd_rn(
                        __fadd_rn(__fmul_rn(w0, d0), __fmul_rn(w1, d1)),
                        __fmul_rn(w2, s0)),
                      __fmul_rn(w3, s1)),
                    b);
        float pr = sigm(t);
        probs[k * 4096 + p] = pr;
        bool pass = pr > 0.53f;
        unsigned long long bal = __ballot(pass);
        if (lane == 0) bits[k * 64 + row] = bal;
        if (pass) {
            aA += 1.0f;
            aM += sigm(x4p[g]);
            atomicMax(&maxp[g], __float_as_uint(pr));
        }
    }
    // per-wave reduce, one LDS atomic per wave
    #pragma unroll
    for (int off = 32; off; off >>= 1) {
        aA += __shfl_down(aA, off);
        aM += __shfl_down(aM, off);
    }
    if (lane == 0) { atomicAdd(&sA, aA); atomicAdd(&sM, aM); }
    __syncthreads();
    if (tid == 0) { areas[k] = sA; msum[k] = sM; }
}

// Fused: blocks [0,256) = winner labeling; blocks [256,512) = pairwise IoU.
__global__ __launch_bounds__(256) void k_labpairs(const int* __restrict__ cnt,
        const int* __restrict__ iy0, const int* __restrict__ ix0,
        const float* __restrict__ probs, const unsigned int* __restrict__ maxp,
        int* __restrict__ lab,
        const unsigned long long* __restrict__ bits,
        const float* __restrict__ areas,
        unsigned long long* __restrict__ adj) {
    int bid = blockIdx.x, tid = threadIdx.x;
    if (bid < KK) {
        int k = bid;
        int c = *cnt; if (c > KK) c = KK;
        if (k >= c) return;
        int gy0 = iy0[k], gx0 = ix0[k];
        for (int q = 0; q < 16; ++q) {
            int p = tid + (q << 8);
            float pr = probs[k * 4096 + p];
            if (pr > 0.53f) {
                int r = p >> 6, cc = p & 63;
                int g = (gy0 + r) * WWI + gx0 + cc;
                if (pr >= __uint_as_float(maxp[g])) atomicMax(&lab[g], k + 1);
            }
        }
    } else {
        int a = bid - KK, b = tid;
        __shared__ unsigned long long rowA[64];
        __shared__ int say0, sax0;
        if (tid < 64) rowA[tid] = bits[a * 64 + tid];
        if (tid == 0) { say0 = iy0[a]; sax0 = ix0[a]; }
        __syncthreads();
        int ay0 = say0, ax0 = sax0;
        int by0 = iy0[b], bx0 = ix0[b];
        int yl = max(ay0, by0), yh = min(ay0 + SSW, by0 + SSW);
        int xl = max(ax0, bx0), xh = min(ax0 + SSW, bx0 + SSW);
        int inter = 0;
        if (yl < yh && xl < xh) {
            int wdt = xh - xl;
            unsigned long long cmask = (wdt >= 64) ? ~0ull : ((1ull << wdt) - 1ull);
            int sa = xl - ax0, sb = xl - bx0;
            for (int y = yl; y < yh; ++y) {
                unsigned long long wa = rowA[y - ay0] >> sa;
                unsigned long long wb = bits[b * 64 + (y - by0)] >> sb;
                inter += __popcll(wa & wb & cmask);
            }
        }
        float fi = (float)inter;
        float uni = __fsub_rn(__fadd_rn(areas[a], areas[b]), fi);
        bool adjb = (fi / fmaxf(uni, 1.0f)) > 0.3f;
        unsigned long long bal = __ballot(adjb);
        if ((tid & 63) == 0) adj[a * 4 + (tid >> 6)] = bal;
    }
}

__global__ __launch_bounds__(256) void k_cc(const unsigned long long* __restrict__ adj,
        const float* __restrict__ areas, const float* __restrict__ msum,
        const int* __restrict__ cnt, int* __restrict__ finalmap) {
    __shared__ unsigned long long adjS[KK][4];
    __shared__ int lbl[KK];
    __shared__ unsigned char rem[KK];
    __shared__ int changed;
    int i = threadIdx.x;
    for (int w = 0; w < 4; ++w) adjS[i][w] = adj[i * 4 + w];
    lbl[i] = i;
    __syncthreads();
    for (int it = 0; it < 32; ++it) {
        int m = KK;
        for (int w = 0; w < 4; ++w) {
            unsigned long long bb = adjS[i][w];
            while (bb) {
                int j = __ffsll((unsigned long long)bb) - 1;
                int v = lbl[(w << 6) | j];
                m = v < m ? v : m;
                bb &= bb - 1;
            }
        }
        if (i == 0) changed = 0;
        __syncthreads();
        if (m != lbl[i]) { lbl[i] = m; atomicOr(&changed, 1); }
        __syncthreads();
        if (!changed) break;   // converged: further iterations are identity
    }
    float area = areas[i];
    bool validf = i < *cnt;
    float mean = msum[i] / fmaxf(area, 1.0f);
    rem[i] = (unsigned char)(!((mean > 0.0f) && (area > 10.0f) && validf));
    __syncthreads();
    int root = lbl[i];
    int rc = root < 255 ? root : 255;
    finalmap[i] = rem[rc] ? 0 : (root + 1);
}

__global__ void k_final(const int* __restrict__ lab, const int* __restrict__ finalmap,
                        float* __restrict__ labels) {
    int p = blockIdx.x * blockDim.x + threadIdx.x;
    if (p < HWN) {
        int l = lab[p];
        labels[p] = l > 0 ? (float)finalmap[l - 1] : 0.0f;
    }
}

extern "C" void kernel_launch(void* const* d_in, const int* in_sizes, int n_in,
                              void* d_out, int out_size, void* d_ws, size_t ws_size,
                              hipStream_t stream) {
    const float* x  = (const float*)d_in[0];
    const float* wc = (const float*)d_in[1];
    const float* bc = (const float*)d_in[2];
    float* labels = (float*)d_out;
    float* probs  = (float*)d_out + HWN;

    char* ws = (char*)d_ws;
    unsigned int*       maxp    = (unsigned int*)(ws + OFF_MAXP);
    int*                lab     = (int*)(ws + OFF_LAB);
    unsigned long long* bits    = (unsigned long long*)(ws + OFF_BITS);
    float*              areas   = (float*)(ws + OFF_AREA);
    float*              msum    = (float*)(ws + OFF_MSUM);
    int*                iy0     = (int*)(ws + OFF_WY0);
    int*                ix0     = (int*)(ws + OFF_WX0);
    int*                fmap    = (int*)(ws + OFF_FINAL);
    int*                cnt     = (int*)(ws + OFF_CNT);
    unsigned long long* adj     = (unsigned long long*)(ws + OFF_ADJ);
    unsigned long long* cand    = (unsigned long long*)(ws + OFF_CAND);
    int*                rankbuf = (int*)(ws + OFF_RANK);

    k_front   <<<NBLK, 256, 0, stream>>>(x + 4 * HWN, cand, maxp, lab, bits,
                                         areas, msum, iy0, ix0, rankbuf, cnt);
    k_rank1   <<<dim3(CAND_CAP / 256, CAND_CAP / 256), 256, 0, stream>>>(cand, rankbuf, cnt);
    k_win2    <<<CAND_CAP + KK, 256, 0, stream>>>(x, wc, bc, cand, rankbuf, cnt,
                                                  probs, maxp, bits, areas, msum, iy0, ix0);
    k_labpairs<<<2 * KK, 256, 0, stream>>>(cnt, iy0, ix0, probs, maxp, lab,
                                           bits, areas, adj);
    k_cc      <<<1, 256, 0, stream>>>(adj, areas, msum, cnt, fmap);
    k_final   <<<HWN / 256, 256, 0, stream>>>(lab, fmap, labels);
}